// Round 5
// baseline (103.661 us; speedup 1.0000x reference)
//
#include <hip/hip_runtime.h>

// SimpleUnsharedPatchScorer: scores[b,p] = sum_d patches[b,p,d]*W[p,d] + bias[p]
// where patches is the torch-unfold-scrambled view:
//   l = p*768+d,  l = i*9408 + j*588 + c*196 + h*14 + w  (i,j in [0,16), c in [0,3), h,w in [0,14))
//   value = x[b, c, 16*h+i, 16*w+j]
//
// Gather-dot design: 1 wave per patch, 12 scalar x loads/lane (stride-64B gather,
// L2 assembles lines), coalesced weight loads, shfl_xor reduce.
// Grid = q*256 + b so an image's 8 blocks land on the same XCD (b mod 8).

#define NPATCH 196
#define DFEAT  768
#define IMGSZ  224

__global__ __launch_bounds__(256) void patch_score_kernel(
    const float* __restrict__ x,       // [256,3,224,224]
    const float* __restrict__ weight,  // [196,768] (flat = [150528])
    const float* __restrict__ bias,    // [196]
    float* __restrict__ out)           // [256,196]
{
    const int bx   = blockIdx.x;
    const int b    = bx & 255;   // image index
    const int q    = bx >> 8;    // patch chunk 0..7
    const int p0   = q * 25;
    const int pend = (p0 + 25 < NPATCH) ? (p0 + 25) : NPATCH;
    const int lane = threadIdx.x & 63;
    const int wave = threadIdx.x >> 6;

    const float* __restrict__ xb = x + (size_t)b * (3 * IMGSZ * IMGSZ);

    for (int p = p0 + wave; p < pend; p += 4) {
        float acc = 0.0f;
        const int base = p * DFEAT;
        #pragma unroll
        for (int it = 0; it < 12; ++it) {
            const int l  = base + it * 64 + lane;
            // decode mixed-radix digits of l: (i,j,c,h,w) with strides 9408/588/196/14/1
            const int i_ = l / 9408;
            const int r1 = l - i_ * 9408;
            const int j_ = r1 / 588;
            const int r2 = r1 - j_ * 588;
            const int c_ = r2 / 196;
            const int r3 = r2 - c_ * 196;
            const int h_ = r3 / 14;
            const int w_ = r3 - h_ * 14;
            const int xi = c_ * (IMGSZ * IMGSZ) + (h_ * 16 + i_) * IMGSZ + (w_ * 16 + j_);
            acc += xb[xi] * weight[l];
        }
        // full-wave butterfly reduction (wave = 64 lanes)
        #pragma unroll
        for (int off = 32; off > 0; off >>= 1)
            acc += __shfl_xor(acc, off, 64);
        if (lane == 0)
            out[b * NPATCH + p] = acc + bias[p];
    }
}

extern "C" void kernel_launch(void* const* d_in, const int* in_sizes, int n_in,
                              void* d_out, int out_size, void* d_ws, size_t ws_size,
                              hipStream_t stream) {
    const float* x      = (const float*)d_in[0];
    const float* weight = (const float*)d_in[1];
    const float* bias   = (const float*)d_in[2];
    float* out          = (float*)d_out;

    dim3 grid(8 * 256);   // 8 patch chunks x 256 images; b = blockIdx & 255 -> XCD co-location
    dim3 block(256);
    patch_score_kernel<<<grid, block, 0, stream>>>(x, weight, bias, out);
}